// Round 1
// baseline (539.155 us; speedup 1.0000x reference)
//
#include <hip/hip_runtime.h>

// GaussianKernel: out[B, HW, OUT] = exp(-(||x||^2 - 2 x.w + ||w||^2)) + b
// x: [B,H,W,C] fp32 (B=16,H=W=128,C=32) -> rows = B*H*W = 262144, row length C=32
// w: [C, OUT] fp32 (OUT=128), b: [OUT] fp32
// All fp32 math (no fp32 MFMA on CDNA4; memory-bound anyway).

constexpr int C_DIM  = 32;
constexpr int OUT_DIM = 128;
constexpr int ROWS_PER_WAVE = 32;
constexpr int WAVES_PER_BLOCK = 4;
constexpr float LOG2E = 1.4426950408889634f;

__global__ __launch_bounds__(256, 4)
void gaussian_rbf_kernel(const float* __restrict__ x,
                         const float* __restrict__ w,
                         const float* __restrict__ bias,
                         float* __restrict__ out,
                         int total_rows)
{
    const int lane = threadIdx.x & 63;
    const int wid  = threadIdx.x >> 6;
    const long wave_global = (long)blockIdx.x * WAVES_PER_BLOCK + wid;
    const long row_base = wave_global * ROWS_PER_WAVE;
    if (row_base >= total_rows) return;

    const int o0 = lane;        // output column 0 for this lane
    const int o1 = lane + 64;   // output column 1 for this lane

    // Stage this lane's two w-columns in registers; precompute ||w||^2.
    float w0[C_DIM], w1[C_DIM];
    float wsq0 = 0.f, wsq1 = 0.f;
#pragma unroll
    for (int c = 0; c < C_DIM; ++c) {
        w0[c] = w[c * OUT_DIM + o0];
        w1[c] = w[c * OUT_DIM + o1];
        wsq0 = fmaf(w0[c], w0[c], wsq0);
        wsq1 = fmaf(w1[c], w1[c], wsq1);
    }
    const float b0 = bias[o0];
    const float b1 = bias[o1];
    // exp(-d) = 2^(-log2e * d); fold -log2e*||w||^2 into a per-lane constant.
    const float base0 = -LOG2E * wsq0;
    const float base1 = -LOG2E * wsq1;

    const long row_end = (row_base + ROWS_PER_WAVE < (long)total_rows)
                           ? row_base + ROWS_PER_WAVE : (long)total_rows;

    for (long row = row_base; row < row_end; ++row) {
        // Broadcast-load the whole 32-float x row (all lanes same address:
        // hardware coalesces to one 16B fetch per instruction).
        const float4* xr = reinterpret_cast<const float4*>(x + row * C_DIM);
        float4 xv[8];
#pragma unroll
        for (int k = 0; k < 8; ++k) xv[k] = xr[k];

        float xs[C_DIM];
#pragma unroll
        for (int k = 0; k < 8; ++k) {
            xs[4 * k + 0] = xv[k].x;
            xs[4 * k + 1] = xv[k].y;
            xs[4 * k + 2] = xv[k].z;
            xs[4 * k + 3] = xv[k].w;
        }

        float xsq = 0.f, d0 = 0.f, d1 = 0.f;
#pragma unroll
        for (int c = 0; c < C_DIM; ++c) {
            xsq = fmaf(xs[c], xs[c], xsq);
            d0  = fmaf(xs[c], w0[c], d0);
            d1  = fmaf(xs[c], w1[c], d1);
        }

        // arg = -log2e*xsq + 2*log2e*dot - log2e*wsq
        const float t0 = fmaf(xsq, -LOG2E, base0);
        const float t1 = fmaf(xsq, -LOG2E, base1);
        const float a0 = fmaf(d0, 2.f * LOG2E, t0);
        const float a1 = fmaf(d1, 2.f * LOG2E, t1);

        float* op = out + row * OUT_DIM;
        op[o0] = exp2f(a0) + b0;   // v_exp_f32
        op[o1] = exp2f(a1) + b1;
    }
}

extern "C" void kernel_launch(void* const* d_in, const int* in_sizes, int n_in,
                              void* d_out, int out_size, void* d_ws, size_t ws_size,
                              hipStream_t stream) {
    const float* x = (const float*)d_in[0];
    const float* w = (const float*)d_in[1];
    const float* b = (const float*)d_in[2];
    float* out = (float*)d_out;

    const int total_rows = in_sizes[0] / C_DIM;  // 262144
    const int rows_per_block = ROWS_PER_WAVE * WAVES_PER_BLOCK;  // 128
    const int nblocks = (total_rows + rows_per_block - 1) / rows_per_block;  // 2048

    gaussian_rbf_kernel<<<nblocks, 256, 0, stream>>>(x, w, b, out, total_rows);
}